// Round 16
// baseline (90.719 us; speedup 1.0000x reference)
//
#include <hip/hip_runtime.h>
#include <hip/hip_bf16.h>

#define B_ 8
#define T_ 768
#define H_ 128
#define F_ 10

using short8v = __attribute__((ext_vector_type(8))) short;
using f32x4   = __attribute__((ext_vector_type(4))) float;

__device__ __forceinline__ float bf2f(unsigned short s) {
  union { unsigned int u; float f; } w;
  w.u = ((unsigned int)s) << 16;
  return w.f;
}
__device__ __forceinline__ unsigned short f2bf(float x) {
  __hip_bfloat16 h = __float2bfloat16(x);  // RN
  return *reinterpret_cast<unsigned short*>(&h);
}
union Pk8 { uint4 u4; unsigned short s[8]; };

// ---------------------------------------------------------------------------
// r10_PV: V -> row-major fragments (rows = T index, K = H dim), hi/lo. (verified)
// ---------------------------------------------------------------------------
__global__ __launch_bounds__(256) void r10_PV(const float* __restrict__ V,
                                              unsigned short* __restrict__ VFh,
                                              unsigned short* __restrict__ VFl) {
  const int task = blockIdx.x * 256 + threadIdx.x;
  const int b  = task / (T_ * 16);
  const int r  = task % (T_ * 16);
  const int j  = r >> 4;
  const int ko = r & 15;
  const float* src = V + ((size_t)b * T_ + j) * H_ + ko * 8;
  const float4 v0 = *reinterpret_cast<const float4*>(src);
  const float4 v1 = *reinterpret_cast<const float4*>(src + 4);
  const float vv[8] = {v0.x, v0.y, v0.z, v0.w, v1.x, v1.y, v1.z, v1.w};
  Pk8 hi, lo;
#pragma unroll
  for (int e = 0; e < 8; ++e) {
    const unsigned short h = f2bf(vv[e]);
    hi.s[e] = h;
    lo.s[e] = f2bf(vv[e] - bf2f(h));
  }
  const size_t frag = ((size_t)b * 48 + (j >> 4)) * 4 + (ko >> 2);
  const size_t off = frag * 512 + ((size_t)((j & 15) + 16 * (ko & 3))) * 8;
  *reinterpret_cast<uint4*>(VFh + off) = hi.u4;
  *reinterpret_cast<uint4*>(VFl + off) = lo.u4;
}

// ---------------------------------------------------------------------------
// r12_PW2: W -> B-operand fragments (K = h, N = k), hi/lo.  (verified)
// ---------------------------------------------------------------------------
__global__ __launch_bounds__(256) void r12_PW2(const float* __restrict__ W,
                                               unsigned short* __restrict__ WFh,
                                               unsigned short* __restrict__ WFl) {
  const int tid = blockIdx.x * 256 + threadIdx.x;  // < 320*64
  const int frag = tid >> 6;
  const int l    = tid & 63;
  const int f    = frag >> 5;
  const int rest = frag & 31;
  const int n    = rest >> 2;
  const int ks   = rest & 3;
  const int k  = n * 16 + (l & 15);
  const int h0 = ks * 32 + ((l >> 4) * 8);
  Pk8 hi, lo;
#pragma unroll
  for (int e = 0; e < 8; ++e) {
    const float v = W[((size_t)f * H_ + h0 + e) * H_ + k];
    const unsigned short hh = f2bf(v);
    hi.s[e] = hh;
    lo.s[e] = f2bf(v - bf2f(hh));
  }
  const size_t off = (size_t)frag * 512 + (size_t)l * 8;
  *reinterpret_cast<uint4*>(WFh + off) = hi.u4;
  *reinterpret_cast<uint4*>(WFl + off) = lo.u4;
}

// ---------------------------------------------------------------------------
// r12_A: U = V @ W via split-bf16 MFMA -> UF fragments.  (verified, r13 swizzle)
// ---------------------------------------------------------------------------
__global__ __launch_bounds__(256) void r12_A(const unsigned short* __restrict__ VFh,
                                             const unsigned short* __restrict__ VFl,
                                             const unsigned short* __restrict__ WFh,
                                             const unsigned short* __restrict__ WFl,
                                             unsigned short* __restrict__ UFh,
                                             unsigned short* __restrict__ UFl) {
  __shared__ __align__(16) float fl[8192];
  const int blk = blockIdx.x;
  const int x     = blk & 7;        // XCD under round-robin dispatch
  const int local = blk >> 3;       // 0..119
  const int panel = x * 12 + local / 10;  // 0..95 (b,it)-panel
  const int f     = local % 10;
  const int b  = panel / 12;
  const int it = panel % 12;
  const int t  = threadIdx.x;
  const int w  = t >> 6;
  const int l  = t & 63;

  short8v Ah[4], Al[4];
#pragma unroll
  for (int ks = 0; ks < 4; ++ks) {
    const size_t off = (((size_t)b * 48 + it * 4 + w) * 4 + ks) * 512 + (size_t)l * 8;
    Ah[ks] = *reinterpret_cast<const short8v*>(VFh + off);
    Al[ks] = *reinterpret_cast<const short8v*>(VFl + off);
  }

  f32x4 acc[8];
#pragma unroll
  for (int n = 0; n < 8; ++n)
#pragma unroll
    for (int q = 0; q < 4; ++q) acc[n][q] = 0.f;

#pragma unroll
  for (int n = 0; n < 8; ++n)
#pragma unroll
    for (int ks = 0; ks < 4; ++ks) {
      const size_t off = ((size_t)(f * 8 + n) * 4 + ks) * 512 + (size_t)l * 8;
      const short8v bh = *reinterpret_cast<const short8v*>(WFh + off);
      const short8v bl = *reinterpret_cast<const short8v*>(WFl + off);
      acc[n] = __builtin_amdgcn_mfma_f32_16x16x32_bf16(Ah[ks], bh, acc[n], 0, 0, 0);
      acc[n] = __builtin_amdgcn_mfma_f32_16x16x32_bf16(Al[ks], bh, acc[n], 0, 0, 0);
      acc[n] = __builtin_amdgcn_mfma_f32_16x16x32_bf16(Ah[ks], bl, acc[n], 0, 0, 0);
    }

#pragma unroll
  for (int n = 0; n < 8; ++n)
#pragma unroll
    for (int q = 0; q < 4; ++q) {
      const int i_loc = w * 16 + (l >> 4) * 4 + q;
      const int k = n * 16 + (l & 15);
      const int ll = (i_loc & 15) + 16 * ((k >> 3) & 3);
      fl[((w * 4 + (k >> 5)) << 9) + ll * 8 + (k & 7)] = acc[n][q];
    }
  __syncthreads();
  const size_t ufbase = ((size_t)(b * F_ + f) * 192 + it * 16) * 512;
#pragma unroll
  for (int rr = 0; rr < 4; ++rr) {
    const int idx = rr * 2048 + t * 8;
    const float4 v0 = *reinterpret_cast<const float4*>(&fl[idx]);
    const float4 v1 = *reinterpret_cast<const float4*>(&fl[idx + 4]);
    const float vv[8] = {v0.x, v0.y, v0.z, v0.w, v1.x, v1.y, v1.z, v1.w};
    Pk8 hi, lo;
#pragma unroll
    for (int e = 0; e < 8; ++e) {
      const unsigned short h = f2bf(vv[e]);
      hi.s[e] = h;
      lo.s[e] = f2bf(vv[e] - bf2f(h));
    }
    *reinterpret_cast<uint4*>(UFh + ufbase + idx) = hi.u4;
    *reinterpret_cast<uint4*>(UFl + ufbase + idx) = lo.u4;
  }
}

// ---------------------------------------------------------------------------
// r16_B: S = max_f U_f V^T via split-bf16 MFMA.  512 threads = 8 waves:
// wave (g,w) with g = f-group (f in [g*5, g*5+5)), w = i-subtile.  Halves the
// per-wave serial f-chain and doubles waves/CU vs r10_B.  Partials merged by
// exact fmax through LDS.  Same r13 XCD panel swizzle.  grid = 1152.
// ---------------------------------------------------------------------------
__global__ __launch_bounds__(512) void r16_B(const unsigned short* __restrict__ UFh,
                                             const unsigned short* __restrict__ UFl,
                                             const unsigned short* __restrict__ VFh,
                                             const unsigned short* __restrict__ VFl,
                                             float* __restrict__ S) {
  __shared__ __align__(16) float sMg[2][4][16][64];  // 32 KB
  const int blk = blockIdx.x;
  const int x     = blk & 7;
  const int local = blk >> 3;             // 0..143
  const int panel = x * 12 + local / 12;  // 0..95
  const int jt    = local % 12;
  const int b  = panel / 12;
  const int it = panel % 12;
  const int t  = threadIdx.x;
  const int wid = t >> 6;   // 0..7
  const int w   = wid & 3;  // i-subtile
  const int g   = wid >> 2; // f-group
  const int l   = t & 63;

  short8v Bh[4][4], Bl[4][4];
#pragma unroll
  for (int n = 0; n < 4; ++n)
#pragma unroll
    for (int ks = 0; ks < 4; ++ks) {
      const size_t off =
          (((size_t)b * 48 + jt * 4 + n) * 4 + ks) * 512 + (size_t)l * 8;
      Bh[n][ks] = *reinterpret_cast<const short8v*>(VFh + off);
      Bl[n][ks] = *reinterpret_cast<const short8v*>(VFl + off);
    }

  f32x4 smax[4];
#pragma unroll
  for (int n = 0; n < 4; ++n)
#pragma unroll
    for (int q = 0; q < 4; ++q) smax[n][q] = -3.4e38f;

  for (int fi = 0; fi < 5; ++fi) {
    const int f = g * 5 + fi;
    const size_t abase = ((size_t)(b * F_ + f) * 48 + it * 4 + w) * 4;
    short8v Ah[4], Al[4];
#pragma unroll
    for (int ks = 0; ks < 4; ++ks) {
      const size_t off = (abase + ks) * 512 + (size_t)l * 8;
      Ah[ks] = *reinterpret_cast<const short8v*>(UFh + off);
      Al[ks] = *reinterpret_cast<const short8v*>(UFl + off);
    }
    f32x4 acc[4];
#pragma unroll
    for (int n = 0; n < 4; ++n)
#pragma unroll
      for (int q = 0; q < 4; ++q) acc[n][q] = 0.f;
#pragma unroll
    for (int ks = 0; ks < 4; ++ks)
#pragma unroll
      for (int n = 0; n < 4; ++n) {
        acc[n] = __builtin_amdgcn_mfma_f32_16x16x32_bf16(Ah[ks], Bh[n][ks], acc[n], 0, 0, 0);
        acc[n] = __builtin_amdgcn_mfma_f32_16x16x32_bf16(Al[ks], Bh[n][ks], acc[n], 0, 0, 0);
        acc[n] = __builtin_amdgcn_mfma_f32_16x16x32_bf16(Ah[ks], Bl[n][ks], acc[n], 0, 0, 0);
      }
#pragma unroll
    for (int n = 0; n < 4; ++n)
#pragma unroll
      for (int q = 0; q < 4; ++q) smax[n][q] = fmaxf(smax[n][q], acc[n][q]);
  }

  // stash partials (C/D layout: row = (l>>4)*4+q, col = (l&15)+16n)
#pragma unroll
  for (int n = 0; n < 4; ++n)
#pragma unroll
    for (int q = 0; q < 4; ++q)
      sMg[g][w][(l >> 4) * 4 + q][(l & 15) + 16 * n] = smax[n][q];
  __syncthreads();

  // merge the two f-groups + coalesced store: 4096 floats, 8 per thread
  const int w2  = t >> 7;        // 0..3
  const int rem = t & 127;
  const int row = rem >> 3;      // 0..15
  const int c8  = (rem & 7) * 8; // 0..56
  const float4 a0 = *reinterpret_cast<const float4*>(&sMg[0][w2][row][c8]);
  const float4 a1 = *reinterpret_cast<const float4*>(&sMg[0][w2][row][c8 + 4]);
  const float4 b0 = *reinterpret_cast<const float4*>(&sMg[1][w2][row][c8]);
  const float4 b1 = *reinterpret_cast<const float4*>(&sMg[1][w2][row][c8 + 4]);
  float4 o0 = make_float4(fmaxf(a0.x, b0.x), fmaxf(a0.y, b0.y),
                          fmaxf(a0.z, b0.z), fmaxf(a0.w, b0.w));
  float4 o1 = make_float4(fmaxf(a1.x, b1.x), fmaxf(a1.y, b1.y),
                          fmaxf(a1.z, b1.z), fmaxf(a1.w, b1.w));
  float* dst = S + ((size_t)b * T_ + it * 64 + w2 * 16 + row) * T_ + jt * 64 + c8;
  *reinterpret_cast<float4*>(dst)     = o0;
  *reinterpret_cast<float4*>(dst + 4) = o1;
}

// ---------------------------------------------------------------------------
// r11_PW: V -> PV-B fragments (j as K dim, h as N dim), hi/lo.  (verified)
// ---------------------------------------------------------------------------
__global__ __launch_bounds__(256) void r11_PW(const float* __restrict__ V,
                                              unsigned short* __restrict__ VPh,
                                              unsigned short* __restrict__ VPl) {
  const int tid = blockIdx.x * 256 + threadIdx.x;  // < 98304
  const int h    = tid & 127;
  const int rest = tid >> 7;
  const int jo   = rest % 96;
  const int b    = rest / 96;
  const int j0   = jo * 8;

  Pk8 hi, lo;
#pragma unroll
  for (int e = 0; e < 8; ++e) {
    const float v = V[((size_t)b * T_ + j0 + e) * H_ + h];
    const unsigned short hh = f2bf(v);
    hi.s[e] = hh;
    lo.s[e] = f2bf(v - bf2f(hh));
  }
  const size_t frag = ((size_t)b * 8 + (h >> 4)) * 24 + (j0 >> 5);
  const size_t off = frag * 512 + ((size_t)((h & 15) + 16 * ((j0 >> 3) & 3))) * 8;
  *reinterpret_cast<uint4*>(VPh + off) = hi.u4;
  *reinterpret_cast<uint4*>(VPl + off) = lo.u4;
}

// ---------------------------------------------------------------------------
// r15_C: softmax -> P bf16 in LDS -> PV via MFMA.  (verified, round 15)
// ---------------------------------------------------------------------------
__global__ __launch_bounds__(512) void r15_C(const unsigned short* __restrict__ VPh,
                                             const unsigned short* __restrict__ VPl,
                                             const float* __restrict__ S,
                                             float* __restrict__ O) {
  __shared__ __align__(16) unsigned short sP[16][776];
  __shared__ float sInv[16];
  const int blk = blockIdx.x;
  const int b    = blk & 7;
  const int it16 = blk >> 3;  // 0..47
  const int t  = threadIdx.x;
  const int r  = t >> 5;   // row 0..15
  const int c  = t & 31;   // lane-in-row (32 lanes)

  const float* Srow = S + (size_t)(b * T_ + it16 * 16) * T_;

  float4 buf[6];
  float m = -3.4e38f;
#pragma unroll
  for (int q = 0; q < 6; ++q) {
    const int j4 = c + q * 32;
    const float4 x = *reinterpret_cast<const float4*>(&Srow[r * T_ + j4 * 4]);
    buf[q] = x;
    m = fmaxf(m, fmaxf(fmaxf(x.x, x.y), fmaxf(x.z, x.w)));
  }
  m = fmaxf(m, __shfl_xor(m, 1));
  m = fmaxf(m, __shfl_xor(m, 2));
  m = fmaxf(m, __shfl_xor(m, 4));
  m = fmaxf(m, __shfl_xor(m, 8));
  m = fmaxf(m, __shfl_xor(m, 16));

  float l = 0.f;
#pragma unroll
  for (int q = 0; q < 6; ++q) {
    const int j4 = c + q * 32;
    float4 e;
    e.x = expf(buf[q].x - m);
    e.y = expf(buf[q].y - m);
    e.z = expf(buf[q].z - m);
    e.w = expf(buf[q].w - m);
    l += (e.x + e.y) + (e.z + e.w);
    ushort4 pb;
    pb.x = f2bf(e.x); pb.y = f2bf(e.y); pb.z = f2bf(e.z); pb.w = f2bf(e.w);
    *reinterpret_cast<ushort4*>(&sP[r][j4 * 4]) = pb;
  }
  l += __shfl_xor(l, 1);
  l += __shfl_xor(l, 2);
  l += __shfl_xor(l, 4);
  l += __shfl_xor(l, 8);
  l += __shfl_xor(l, 16);
  if (c == 0) sInv[r] = 1.0f / l;
  __syncthreads();

  const int w  = t >> 6;   // 0..7
  const int lv = t & 63;
  f32x4 acc;
#pragma unroll
  for (int q = 0; q < 4; ++q) acc[q] = 0.f;

  const int arow = lv & 15;
  const int koct = lv >> 4;
#pragma unroll
  for (int ks = 0; ks < 24; ++ks) {
    const short8v pa =
        *reinterpret_cast<const short8v*>(&sP[arow][ks * 32 + koct * 8]);
    const size_t f0 = (((size_t)b * 8 + w) * 24 + ks) * 512 + (size_t)lv * 8;
    const short8v vh = *reinterpret_cast<const short8v*>(VPh + f0);
    const short8v vl = *reinterpret_cast<const short8v*>(VPl + f0);
    acc = __builtin_amdgcn_mfma_f32_16x16x32_bf16(pa, vh, acc, 0, 0, 0);
    acc = __builtin_amdgcn_mfma_f32_16x16x32_bf16(pa, vl, acc, 0, 0, 0);
  }

  const int hcol = lv & 15;
#pragma unroll
  for (int q = 0; q < 4; ++q) {
    const int irow = (lv >> 4) * 4 + q;
    const float inv = sInv[irow];
    const size_t obase = ((size_t)(b * T_ + it16 * 16 + irow)) * H_;
    O[obase + w * 16 + hcol] = acc[q] * inv;
  }
}

// ---------------------------------------------------------------------------
extern "C" void kernel_launch(void* const* d_in, const int* in_sizes, int n_in,
                              void* d_out, int out_size, void* d_ws, size_t ws_size,
                              hipStream_t stream) {
  const float* V = (const float*)d_in[0];  // f32 [B,T,H]
  const float* W = (const float*)d_in[1];  // f32 [F,H,H]
  if (n_in >= 2 && in_sizes[0] == F_ * H_ * H_) {
    V = (const float*)d_in[1];
    W = (const float*)d_in[0];
  }
  float* O = (float*)d_out;  // f32 [B,T,H]

  const size_t s_bytes  = (size_t)B_ * T_ * T_ * 4;       // 18,874,368
  const size_t uf_bytes = (size_t)B_ * F_ * H_ * T_ * 2;  // 15,728,640
  const size_t vf_bytes = (size_t)B_ * H_ * T_ * 2;       //  1,572,864
  const size_t wf_bytes = (size_t)F_ * H_ * H_ * 2;       //    327,680
  const size_t need = s_bytes + 2 * uf_bytes + 2 * vf_bytes;  // 53,477,376
  if (ws_size < need) return;

  char* base = (char*)d_ws;
  float* S  = (float*)base;  // [B,T,T]
  // WF overlays S: read only by r12_A, which completes before r16_B writes S.
  unsigned short* WFh = (unsigned short*)base;
  unsigned short* WFl = (unsigned short*)(base + wf_bytes);
  unsigned short* UFh = (unsigned short*)(base + s_bytes);
  unsigned short* UFl = (unsigned short*)(base + s_bytes + uf_bytes);
  unsigned short* VFh = (unsigned short*)(base + s_bytes + 2 * uf_bytes);
  unsigned short* VFl = (unsigned short*)(base + s_bytes + 2 * uf_bytes + vf_bytes);
  // VP overlays UF: written by r11_PW only after r16_B (UF's last reader).
  unsigned short* VPh = UFh;
  unsigned short* VPl = UFh + vf_bytes / 2;

  r10_PV<<<B_ * T_ * 16 / 256, 256, 0, stream>>>(V, VFh, VFl);
  r12_PW2<<<F_ * 8 * 4 * 64 / 256, 256, 0, stream>>>(W, WFh, WFl);
  r12_A<<<B_ * F_ * (T_ / 64), 256, 0, stream>>>(VFh, VFl, WFh, WFl, UFh, UFl);
  r16_B<<<B_ * (T_ / 64) * (T_ / 64), 512, 0, stream>>>(UFh, UFl, VFh, VFl, S);
  r11_PW<<<B_ * 96 * 128 / 256, 256, 0, stream>>>(V, VPh, VPl);
  r15_C<<<B_ * (T_ / 16), 512, 0, stream>>>(VPh, VPl, S, O);
}

// Round 17
// 84.546 us; speedup vs baseline: 1.0730x; 1.0730x over previous
//
#include <hip/hip_runtime.h>
#include <hip/hip_bf16.h>

#define B_ 8
#define T_ 768
#define H_ 128
#define F_ 10

using short8v = __attribute__((ext_vector_type(8))) short;
using f32x4   = __attribute__((ext_vector_type(4))) float;

__device__ __forceinline__ float bf2f(unsigned short s) {
  union { unsigned int u; float f; } w;
  w.u = ((unsigned int)s) << 16;
  return w.f;
}
__device__ __forceinline__ unsigned short f2bf(float x) {
  __hip_bfloat16 h = __float2bfloat16(x);  // RN
  return *reinterpret_cast<unsigned short*>(&h);
}
union Pk8 { uint4 u4; unsigned short s[8]; };

// ---------------------------------------------------------------------------
// r10_PV: V -> row-major fragments (rows = T index, K = H dim), hi/lo. (verified)
// ---------------------------------------------------------------------------
__global__ __launch_bounds__(256) void r10_PV(const float* __restrict__ V,
                                              unsigned short* __restrict__ VFh,
                                              unsigned short* __restrict__ VFl) {
  const int task = blockIdx.x * 256 + threadIdx.x;
  const int b  = task / (T_ * 16);
  const int r  = task % (T_ * 16);
  const int j  = r >> 4;
  const int ko = r & 15;
  const float* src = V + ((size_t)b * T_ + j) * H_ + ko * 8;
  const float4 v0 = *reinterpret_cast<const float4*>(src);
  const float4 v1 = *reinterpret_cast<const float4*>(src + 4);
  const float vv[8] = {v0.x, v0.y, v0.z, v0.w, v1.x, v1.y, v1.z, v1.w};
  Pk8 hi, lo;
#pragma unroll
  for (int e = 0; e < 8; ++e) {
    const unsigned short h = f2bf(vv[e]);
    hi.s[e] = h;
    lo.s[e] = f2bf(vv[e] - bf2f(h));
  }
  const size_t frag = ((size_t)b * 48 + (j >> 4)) * 4 + (ko >> 2);
  const size_t off = frag * 512 + ((size_t)((j & 15) + 16 * (ko & 3))) * 8;
  *reinterpret_cast<uint4*>(VFh + off) = hi.u4;
  *reinterpret_cast<uint4*>(VFl + off) = lo.u4;
}

// ---------------------------------------------------------------------------
// r12_PW2: W -> B-operand fragments (K = h, N = k), hi/lo.  (verified)
// ---------------------------------------------------------------------------
__global__ __launch_bounds__(256) void r12_PW2(const float* __restrict__ W,
                                               unsigned short* __restrict__ WFh,
                                               unsigned short* __restrict__ WFl) {
  const int tid = blockIdx.x * 256 + threadIdx.x;  // < 320*64
  const int frag = tid >> 6;
  const int l    = tid & 63;
  const int f    = frag >> 5;
  const int rest = frag & 31;
  const int n    = rest >> 2;
  const int ks   = rest & 3;
  const int k  = n * 16 + (l & 15);
  const int h0 = ks * 32 + ((l >> 4) * 8);
  Pk8 hi, lo;
#pragma unroll
  for (int e = 0; e < 8; ++e) {
    const float v = W[((size_t)f * H_ + h0 + e) * H_ + k];
    const unsigned short hh = f2bf(v);
    hi.s[e] = hh;
    lo.s[e] = f2bf(v - bf2f(hh));
  }
  const size_t off = (size_t)frag * 512 + (size_t)l * 8;
  *reinterpret_cast<uint4*>(WFh + off) = hi.u4;
  *reinterpret_cast<uint4*>(WFl + off) = lo.u4;
}

// ---------------------------------------------------------------------------
// r12_A: U = V @ W via split-bf16 MFMA -> UF fragments.  (verified, r13 swizzle)
// ---------------------------------------------------------------------------
__global__ __launch_bounds__(256) void r12_A(const unsigned short* __restrict__ VFh,
                                             const unsigned short* __restrict__ VFl,
                                             const unsigned short* __restrict__ WFh,
                                             const unsigned short* __restrict__ WFl,
                                             unsigned short* __restrict__ UFh,
                                             unsigned short* __restrict__ UFl) {
  __shared__ __align__(16) float fl[8192];
  const int blk = blockIdx.x;
  const int x     = blk & 7;        // XCD under round-robin dispatch
  const int local = blk >> 3;       // 0..119
  const int panel = x * 12 + local / 10;  // 0..95 (b,it)-panel
  const int f     = local % 10;
  const int b  = panel / 12;
  const int it = panel % 12;
  const int t  = threadIdx.x;
  const int w  = t >> 6;
  const int l  = t & 63;

  short8v Ah[4], Al[4];
#pragma unroll
  for (int ks = 0; ks < 4; ++ks) {
    const size_t off = (((size_t)b * 48 + it * 4 + w) * 4 + ks) * 512 + (size_t)l * 8;
    Ah[ks] = *reinterpret_cast<const short8v*>(VFh + off);
    Al[ks] = *reinterpret_cast<const short8v*>(VFl + off);
  }

  f32x4 acc[8];
#pragma unroll
  for (int n = 0; n < 8; ++n)
#pragma unroll
    for (int q = 0; q < 4; ++q) acc[n][q] = 0.f;

#pragma unroll
  for (int n = 0; n < 8; ++n)
#pragma unroll
    for (int ks = 0; ks < 4; ++ks) {
      const size_t off = ((size_t)(f * 8 + n) * 4 + ks) * 512 + (size_t)l * 8;
      const short8v bh = *reinterpret_cast<const short8v*>(WFh + off);
      const short8v bl = *reinterpret_cast<const short8v*>(WFl + off);
      acc[n] = __builtin_amdgcn_mfma_f32_16x16x32_bf16(Ah[ks], bh, acc[n], 0, 0, 0);
      acc[n] = __builtin_amdgcn_mfma_f32_16x16x32_bf16(Al[ks], bh, acc[n], 0, 0, 0);
      acc[n] = __builtin_amdgcn_mfma_f32_16x16x32_bf16(Ah[ks], bl, acc[n], 0, 0, 0);
    }

#pragma unroll
  for (int n = 0; n < 8; ++n)
#pragma unroll
    for (int q = 0; q < 4; ++q) {
      const int i_loc = w * 16 + (l >> 4) * 4 + q;
      const int k = n * 16 + (l & 15);
      const int ll = (i_loc & 15) + 16 * ((k >> 3) & 3);
      fl[((w * 4 + (k >> 5)) << 9) + ll * 8 + (k & 7)] = acc[n][q];
    }
  __syncthreads();
  const size_t ufbase = ((size_t)(b * F_ + f) * 192 + it * 16) * 512;
#pragma unroll
  for (int rr = 0; rr < 4; ++rr) {
    const int idx = rr * 2048 + t * 8;
    const float4 v0 = *reinterpret_cast<const float4*>(&fl[idx]);
    const float4 v1 = *reinterpret_cast<const float4*>(&fl[idx + 4]);
    const float vv[8] = {v0.x, v0.y, v0.z, v0.w, v1.x, v1.y, v1.z, v1.w};
    Pk8 hi, lo;
#pragma unroll
    for (int e = 0; e < 8; ++e) {
      const unsigned short h = f2bf(vv[e]);
      hi.s[e] = h;
      lo.s[e] = f2bf(vv[e] - bf2f(h));
    }
    *reinterpret_cast<uint4*>(UFh + ufbase + idx) = hi.u4;
    *reinterpret_cast<uint4*>(UFl + ufbase + idx) = lo.u4;
  }
}

// ---------------------------------------------------------------------------
// r17_B: S = max_f U_f V^T via split-bf16 MFMA.  512 threads = 8 waves =
// 4 i-subs x 2 j-halves.  Per wave: 16i x 32j x all 10 f.  B-frags (16
// short8v = 64 VGPR) are truly register-resident (r16_B's 128-VGPR B set
// forced per-f reloads -> latency-bound).  A-frags double-buffered across
// the fully-unrolled f-loop (prefetch f+1 under f's 24 MFMAs).  No LDS,
// no merge: each wave stores its own disjoint 16x32 S tile (verified
// pattern).  Same r13 XCD panel swizzle.  grid = 1152.
// ---------------------------------------------------------------------------
__global__ __launch_bounds__(512) void r17_B(const unsigned short* __restrict__ UFh,
                                             const unsigned short* __restrict__ UFl,
                                             const unsigned short* __restrict__ VFh,
                                             const unsigned short* __restrict__ VFl,
                                             float* __restrict__ S) {
  const int blk = blockIdx.x;
  const int x     = blk & 7;
  const int local = blk >> 3;             // 0..143
  const int panel = x * 12 + local / 12;  // 0..95
  const int jt    = local % 12;
  const int b  = panel / 12;
  const int it = panel % 12;
  const int t  = threadIdx.x;
  const int wid = t >> 6;   // 0..7
  const int w   = wid & 3;  // i-subtile
  const int g   = wid >> 2; // j-half: n-frags 2g, 2g+1
  const int l   = t & 63;

  // B fragments: resident for the whole kernel (2 n-frags only)
  short8v Bh[2][4], Bl[2][4];
#pragma unroll
  for (int n2 = 0; n2 < 2; ++n2)
#pragma unroll
    for (int ks = 0; ks < 4; ++ks) {
      const size_t off =
          (((size_t)b * 48 + jt * 4 + (g * 2 + n2)) * 4 + ks) * 512 + (size_t)l * 8;
      Bh[n2][ks] = *reinterpret_cast<const short8v*>(VFh + off);
      Bl[n2][ks] = *reinterpret_cast<const short8v*>(VFl + off);
    }

  f32x4 smax[2];
#pragma unroll
  for (int n2 = 0; n2 < 2; ++n2)
#pragma unroll
    for (int q = 0; q < 4; ++q) smax[n2][q] = -3.4e38f;

  // A double-buffer; f-loop fully unrolled so buffer indices are static
  short8v Ah[2][4], Al[2][4];
#pragma unroll
  for (int ks = 0; ks < 4; ++ks) {
    const size_t off =
        (((size_t)(b * F_ + 0) * 48 + it * 4 + w) * 4 + ks) * 512 + (size_t)l * 8;
    Ah[0][ks] = *reinterpret_cast<const short8v*>(UFh + off);
    Al[0][ks] = *reinterpret_cast<const short8v*>(UFl + off);
  }

#pragma unroll
  for (int f = 0; f < F_; ++f) {
    const int cur = f & 1;
    const int nxt = cur ^ 1;
    if (f + 1 < F_) {
#pragma unroll
      for (int ks = 0; ks < 4; ++ks) {
        const size_t off =
            (((size_t)(b * F_ + f + 1) * 48 + it * 4 + w) * 4 + ks) * 512 +
            (size_t)l * 8;
        Ah[nxt][ks] = *reinterpret_cast<const short8v*>(UFh + off);
        Al[nxt][ks] = *reinterpret_cast<const short8v*>(UFl + off);
      }
    }
    f32x4 acc[2];
#pragma unroll
    for (int n2 = 0; n2 < 2; ++n2)
#pragma unroll
      for (int q = 0; q < 4; ++q) acc[n2][q] = 0.f;
#pragma unroll
    for (int ks = 0; ks < 4; ++ks)
#pragma unroll
      for (int n2 = 0; n2 < 2; ++n2) {
        acc[n2] = __builtin_amdgcn_mfma_f32_16x16x32_bf16(Ah[cur][ks], Bh[n2][ks], acc[n2], 0, 0, 0);
        acc[n2] = __builtin_amdgcn_mfma_f32_16x16x32_bf16(Al[cur][ks], Bh[n2][ks], acc[n2], 0, 0, 0);
        acc[n2] = __builtin_amdgcn_mfma_f32_16x16x32_bf16(Ah[cur][ks], Bl[n2][ks], acc[n2], 0, 0, 0);
      }
#pragma unroll
    for (int n2 = 0; n2 < 2; ++n2)
#pragma unroll
      for (int q = 0; q < 4; ++q) smax[n2][q] = fmaxf(smax[n2][q], acc[n2][q]);
  }

  // store: C/D layout (m89): row = (l>>4)*4+q, col = l&15
  const int i0 = it * 64 + w * 16 + (l >> 4) * 4;
  const int j0 = jt * 64 + g * 32 + (l & 15);
#pragma unroll
  for (int n2 = 0; n2 < 2; ++n2)
#pragma unroll
    for (int q = 0; q < 4; ++q)
      S[((size_t)b * T_ + i0 + q) * T_ + j0 + n2 * 16] = smax[n2][q];
}

// ---------------------------------------------------------------------------
// r11_PW: V -> PV-B fragments (j as K dim, h as N dim), hi/lo.  (verified)
// ---------------------------------------------------------------------------
__global__ __launch_bounds__(256) void r11_PW(const float* __restrict__ V,
                                              unsigned short* __restrict__ VPh,
                                              unsigned short* __restrict__ VPl) {
  const int tid = blockIdx.x * 256 + threadIdx.x;  // < 98304
  const int h    = tid & 127;
  const int rest = tid >> 7;
  const int jo   = rest % 96;
  const int b    = rest / 96;
  const int j0   = jo * 8;

  Pk8 hi, lo;
#pragma unroll
  for (int e = 0; e < 8; ++e) {
    const float v = V[((size_t)b * T_ + j0 + e) * H_ + h];
    const unsigned short hh = f2bf(v);
    hi.s[e] = hh;
    lo.s[e] = f2bf(v - bf2f(hh));
  }
  const size_t frag = ((size_t)b * 8 + (h >> 4)) * 24 + (j0 >> 5);
  const size_t off = frag * 512 + ((size_t)((h & 15) + 16 * ((j0 >> 3) & 3))) * 8;
  *reinterpret_cast<uint4*>(VPh + off) = hi.u4;
  *reinterpret_cast<uint4*>(VPl + off) = lo.u4;
}

// ---------------------------------------------------------------------------
// r15_C: softmax -> P bf16 in LDS -> PV via MFMA.  (verified, round 15)
// ---------------------------------------------------------------------------
__global__ __launch_bounds__(512) void r15_C(const unsigned short* __restrict__ VPh,
                                             const unsigned short* __restrict__ VPl,
                                             const float* __restrict__ S,
                                             float* __restrict__ O) {
  __shared__ __align__(16) unsigned short sP[16][776];
  __shared__ float sInv[16];
  const int blk = blockIdx.x;
  const int b    = blk & 7;
  const int it16 = blk >> 3;  // 0..47
  const int t  = threadIdx.x;
  const int r  = t >> 5;   // row 0..15
  const int c  = t & 31;   // lane-in-row (32 lanes)

  const float* Srow = S + (size_t)(b * T_ + it16 * 16) * T_;

  float4 buf[6];
  float m = -3.4e38f;
#pragma unroll
  for (int q = 0; q < 6; ++q) {
    const int j4 = c + q * 32;
    const float4 x = *reinterpret_cast<const float4*>(&Srow[r * T_ + j4 * 4]);
    buf[q] = x;
    m = fmaxf(m, fmaxf(fmaxf(x.x, x.y), fmaxf(x.z, x.w)));
  }
  m = fmaxf(m, __shfl_xor(m, 1));
  m = fmaxf(m, __shfl_xor(m, 2));
  m = fmaxf(m, __shfl_xor(m, 4));
  m = fmaxf(m, __shfl_xor(m, 8));
  m = fmaxf(m, __shfl_xor(m, 16));

  float l = 0.f;
#pragma unroll
  for (int q = 0; q < 6; ++q) {
    const int j4 = c + q * 32;
    float4 e;
    e.x = expf(buf[q].x - m);
    e.y = expf(buf[q].y - m);
    e.z = expf(buf[q].z - m);
    e.w = expf(buf[q].w - m);
    l += (e.x + e.y) + (e.z + e.w);
    ushort4 pb;
    pb.x = f2bf(e.x); pb.y = f2bf(e.y); pb.z = f2bf(e.z); pb.w = f2bf(e.w);
    *reinterpret_cast<ushort4*>(&sP[r][j4 * 4]) = pb;
  }
  l += __shfl_xor(l, 1);
  l += __shfl_xor(l, 2);
  l += __shfl_xor(l, 4);
  l += __shfl_xor(l, 8);
  l += __shfl_xor(l, 16);
  if (c == 0) sInv[r] = 1.0f / l;
  __syncthreads();

  const int w  = t >> 6;   // 0..7
  const int lv = t & 63;
  f32x4 acc;
#pragma unroll
  for (int q = 0; q < 4; ++q) acc[q] = 0.f;

  const int arow = lv & 15;
  const int koct = lv >> 4;
#pragma unroll
  for (int ks = 0; ks < 24; ++ks) {
    const short8v pa =
        *reinterpret_cast<const short8v*>(&sP[arow][ks * 32 + koct * 8]);
    const size_t f0 = (((size_t)b * 8 + w) * 24 + ks) * 512 + (size_t)lv * 8;
    const short8v vh = *reinterpret_cast<const short8v*>(VPh + f0);
    const short8v vl = *reinterpret_cast<const short8v*>(VPl + f0);
    acc = __builtin_amdgcn_mfma_f32_16x16x32_bf16(pa, vh, acc, 0, 0, 0);
    acc = __builtin_amdgcn_mfma_f32_16x16x32_bf16(pa, vl, acc, 0, 0, 0);
  }

  const int hcol = lv & 15;
#pragma unroll
  for (int q = 0; q < 4; ++q) {
    const int irow = (lv >> 4) * 4 + q;
    const float inv = sInv[irow];
    const size_t obase = ((size_t)(b * T_ + it16 * 16 + irow)) * H_;
    O[obase + w * 16 + hcol] = acc[q] * inv;
  }
}

// ---------------------------------------------------------------------------
extern "C" void kernel_launch(void* const* d_in, const int* in_sizes, int n_in,
                              void* d_out, int out_size, void* d_ws, size_t ws_size,
                              hipStream_t stream) {
  const float* V = (const float*)d_in[0];  // f32 [B,T,H]
  const float* W = (const float*)d_in[1];  // f32 [F,H,H]
  if (n_in >= 2 && in_sizes[0] == F_ * H_ * H_) {
    V = (const float*)d_in[1];
    W = (const float*)d_in[0];
  }
  float* O = (float*)d_out;  // f32 [B,T,H]

  const size_t s_bytes  = (size_t)B_ * T_ * T_ * 4;       // 18,874,368
  const size_t uf_bytes = (size_t)B_ * F_ * H_ * T_ * 2;  // 15,728,640
  const size_t vf_bytes = (size_t)B_ * H_ * T_ * 2;       //  1,572,864
  const size_t wf_bytes = (size_t)F_ * H_ * H_ * 2;       //    327,680
  const size_t need = s_bytes + 2 * uf_bytes + 2 * vf_bytes;  // 53,477,376
  if (ws_size < need) return;

  char* base = (char*)d_ws;
  float* S  = (float*)base;  // [B,T,T]
  // WF overlays S: read only by r12_A, which completes before r17_B writes S.
  unsigned short* WFh = (unsigned short*)base;
  unsigned short* WFl = (unsigned short*)(base + wf_bytes);
  unsigned short* UFh = (unsigned short*)(base + s_bytes);
  unsigned short* UFl = (unsigned short*)(base + s_bytes + uf_bytes);
  unsigned short* VFh = (unsigned short*)(base + s_bytes + 2 * uf_bytes);
  unsigned short* VFl = (unsigned short*)(base + s_bytes + 2 * uf_bytes + vf_bytes);
  // VP overlays UF: written by r11_PW only after r17_B (UF's last reader).
  unsigned short* VPh = UFh;
  unsigned short* VPl = UFh + vf_bytes / 2;

  r10_PV<<<B_ * T_ * 16 / 256, 256, 0, stream>>>(V, VFh, VFl);
  r12_PW2<<<F_ * 8 * 4 * 64 / 256, 256, 0, stream>>>(W, WFh, WFl);
  r12_A<<<B_ * F_ * (T_ / 64), 256, 0, stream>>>(VFh, VFl, WFh, WFl, UFh, UFl);
  r17_B<<<B_ * (T_ / 64) * (T_ / 64), 512, 0, stream>>>(UFh, UFl, VFh, VFl, S);
  r11_PW<<<B_ * 96 * 128 / 256, 256, 0, stream>>>(V, VPh, VPl);
  r15_C<<<B_ * (T_ / 16), 512, 0, stream>>>(VPh, VPl, S, O);
}

// Round 18
// 71.741 us; speedup vs baseline: 1.2645x; 1.1785x over previous
//
#include <hip/hip_runtime.h>
#include <hip/hip_bf16.h>

#define B_ 8
#define T_ 768
#define H_ 128
#define F_ 10

using short8v = __attribute__((ext_vector_type(8))) short;
using f32x4   = __attribute__((ext_vector_type(4))) float;

__device__ __forceinline__ float bf2f(unsigned short s) {
  union { unsigned int u; float f; } w;
  w.u = ((unsigned int)s) << 16;
  return w.f;
}
__device__ __forceinline__ unsigned short f2bf(float x) {
  __hip_bfloat16 h = __float2bfloat16(x);  // RN
  return *reinterpret_cast<unsigned short*>(&h);
}
union Pk8 { uint4 u4; unsigned short s[8]; };

// ---------------------------------------------------------------------------
// r18_P: fused packers (one launch).  Block-level range split:
//   blk   0..383 : r10_PV  (V -> VF row-major frags, K = H)        [verified]
//   blk 384..463 : r12_PW2 (W -> WF B-frags, K = h, N = k)         [verified]
//   blk 464..847 : r11_PW  (V -> VP PV-B-frags, K = j, N = h)      [verified]
// grid = 848.  All bodies byte-identical to their verified originals.
// ---------------------------------------------------------------------------
__global__ __launch_bounds__(256) void r18_P(const float* __restrict__ V,
                                             const float* __restrict__ W,
                                             unsigned short* __restrict__ VFh,
                                             unsigned short* __restrict__ VFl,
                                             unsigned short* __restrict__ WFh,
                                             unsigned short* __restrict__ WFl,
                                             unsigned short* __restrict__ VPh,
                                             unsigned short* __restrict__ VPl) {
  const int blk = blockIdx.x;
  if (blk < 384) {
    const int task = blk * 256 + threadIdx.x;
    const int b  = task / (T_ * 16);
    const int r  = task % (T_ * 16);
    const int j  = r >> 4;
    const int ko = r & 15;
    const float* src = V + ((size_t)b * T_ + j) * H_ + ko * 8;
    const float4 v0 = *reinterpret_cast<const float4*>(src);
    const float4 v1 = *reinterpret_cast<const float4*>(src + 4);
    const float vv[8] = {v0.x, v0.y, v0.z, v0.w, v1.x, v1.y, v1.z, v1.w};
    Pk8 hi, lo;
#pragma unroll
    for (int e = 0; e < 8; ++e) {
      const unsigned short h = f2bf(vv[e]);
      hi.s[e] = h;
      lo.s[e] = f2bf(vv[e] - bf2f(h));
    }
    const size_t frag = ((size_t)b * 48 + (j >> 4)) * 4 + (ko >> 2);
    const size_t off = frag * 512 + ((size_t)((j & 15) + 16 * (ko & 3))) * 8;
    *reinterpret_cast<uint4*>(VFh + off) = hi.u4;
    *reinterpret_cast<uint4*>(VFl + off) = lo.u4;
  } else if (blk < 464) {
    const int tid = (blk - 384) * 256 + threadIdx.x;  // < 20480
    const int frag = tid >> 6;
    const int l    = tid & 63;
    const int f    = frag >> 5;
    const int rest = frag & 31;
    const int n    = rest >> 2;
    const int ks   = rest & 3;
    const int k  = n * 16 + (l & 15);
    const int h0 = ks * 32 + ((l >> 4) * 8);
    Pk8 hi, lo;
#pragma unroll
    for (int e = 0; e < 8; ++e) {
      const float v = W[((size_t)f * H_ + h0 + e) * H_ + k];
      const unsigned short hh = f2bf(v);
      hi.s[e] = hh;
      lo.s[e] = f2bf(v - bf2f(hh));
    }
    const size_t off = (size_t)frag * 512 + (size_t)l * 8;
    *reinterpret_cast<uint4*>(WFh + off) = hi.u4;
    *reinterpret_cast<uint4*>(WFl + off) = lo.u4;
  } else {
    const int tid = (blk - 464) * 256 + threadIdx.x;  // < 98304
    const int h    = tid & 127;
    const int rest = tid >> 7;
    const int jo   = rest % 96;
    const int b    = rest / 96;
    const int j0   = jo * 8;
    Pk8 hi, lo;
#pragma unroll
    for (int e = 0; e < 8; ++e) {
      const float v = V[((size_t)b * T_ + j0 + e) * H_ + h];
      const unsigned short hh = f2bf(v);
      hi.s[e] = hh;
      lo.s[e] = f2bf(v - bf2f(hh));
    }
    const size_t frag = ((size_t)b * 8 + (h >> 4)) * 24 + (j0 >> 5);
    const size_t off = frag * 512 + ((size_t)((h & 15) + 16 * ((j0 >> 3) & 3))) * 8;
    *reinterpret_cast<uint4*>(VPh + off) = hi.u4;
    *reinterpret_cast<uint4*>(VPl + off) = lo.u4;
  }
}

// ---------------------------------------------------------------------------
// r12_A: U = V @ W via split-bf16 MFMA -> UF fragments.  (verified, r13 swizzle)
// ---------------------------------------------------------------------------
__global__ __launch_bounds__(256) void r12_A(const unsigned short* __restrict__ VFh,
                                             const unsigned short* __restrict__ VFl,
                                             const unsigned short* __restrict__ WFh,
                                             const unsigned short* __restrict__ WFl,
                                             unsigned short* __restrict__ UFh,
                                             unsigned short* __restrict__ UFl) {
  __shared__ __align__(16) float fl[8192];
  const int blk = blockIdx.x;
  const int x     = blk & 7;        // XCD under round-robin dispatch
  const int local = blk >> 3;       // 0..119
  const int panel = x * 12 + local / 10;  // 0..95 (b,it)-panel
  const int f     = local % 10;
  const int b  = panel / 12;
  const int it = panel % 12;
  const int t  = threadIdx.x;
  const int w  = t >> 6;
  const int l  = t & 63;

  short8v Ah[4], Al[4];
#pragma unroll
  for (int ks = 0; ks < 4; ++ks) {
    const size_t off = (((size_t)b * 48 + it * 4 + w) * 4 + ks) * 512 + (size_t)l * 8;
    Ah[ks] = *reinterpret_cast<const short8v*>(VFh + off);
    Al[ks] = *reinterpret_cast<const short8v*>(VFl + off);
  }

  f32x4 acc[8];
#pragma unroll
  for (int n = 0; n < 8; ++n)
#pragma unroll
    for (int q = 0; q < 4; ++q) acc[n][q] = 0.f;

#pragma unroll
  for (int n = 0; n < 8; ++n)
#pragma unroll
    for (int ks = 0; ks < 4; ++ks) {
      const size_t off = ((size_t)(f * 8 + n) * 4 + ks) * 512 + (size_t)l * 8;
      const short8v bh = *reinterpret_cast<const short8v*>(WFh + off);
      const short8v bl = *reinterpret_cast<const short8v*>(WFl + off);
      acc[n] = __builtin_amdgcn_mfma_f32_16x16x32_bf16(Ah[ks], bh, acc[n], 0, 0, 0);
      acc[n] = __builtin_amdgcn_mfma_f32_16x16x32_bf16(Al[ks], bh, acc[n], 0, 0, 0);
      acc[n] = __builtin_amdgcn_mfma_f32_16x16x32_bf16(Ah[ks], bl, acc[n], 0, 0, 0);
    }

#pragma unroll
  for (int n = 0; n < 8; ++n)
#pragma unroll
    for (int q = 0; q < 4; ++q) {
      const int i_loc = w * 16 + (l >> 4) * 4 + q;
      const int k = n * 16 + (l & 15);
      const int ll = (i_loc & 15) + 16 * ((k >> 3) & 3);
      fl[((w * 4 + (k >> 5)) << 9) + ll * 8 + (k & 7)] = acc[n][q];
    }
  __syncthreads();
  const size_t ufbase = ((size_t)(b * F_ + f) * 192 + it * 16) * 512;
#pragma unroll
  for (int rr = 0; rr < 4; ++rr) {
    const int idx = rr * 2048 + t * 8;
    const float4 v0 = *reinterpret_cast<const float4*>(&fl[idx]);
    const float4 v1 = *reinterpret_cast<const float4*>(&fl[idx + 4]);
    const float vv[8] = {v0.x, v0.y, v0.z, v0.w, v1.x, v1.y, v1.z, v1.w};
    Pk8 hi, lo;
#pragma unroll
    for (int e = 0; e < 8; ++e) {
      const unsigned short h = f2bf(vv[e]);
      hi.s[e] = h;
      lo.s[e] = f2bf(vv[e] - bf2f(h));
    }
    *reinterpret_cast<uint4*>(UFh + ufbase + idx) = hi.u4;
    *reinterpret_cast<uint4*>(UFl + ufbase + idx) = lo.u4;
  }
}

// ---------------------------------------------------------------------------
// r10_B: S = max_f U_f V^T via split-bf16 MFMA.  (verified r13/r15 version;
// only addition: s_setprio(1) around the MFMA cluster — waves here are
// barrier-free/independent, the favorable regime for setprio.)
// ---------------------------------------------------------------------------
__global__ __launch_bounds__(256) void r10_B(const unsigned short* __restrict__ UFh,
                                             const unsigned short* __restrict__ UFl,
                                             const unsigned short* __restrict__ VFh,
                                             const unsigned short* __restrict__ VFl,
                                             float* __restrict__ S) {
  const int blk = blockIdx.x;
  const int x     = blk & 7;
  const int local = blk >> 3;             // 0..143
  const int panel = x * 12 + local / 12;  // 0..95
  const int jt    = local % 12;
  const int b  = panel / 12;
  const int it = panel % 12;
  const int w  = threadIdx.x >> 6;
  const int l  = threadIdx.x & 63;

  short8v Bh[4][4], Bl[4][4];
#pragma unroll
  for (int n = 0; n < 4; ++n)
#pragma unroll
    for (int ks = 0; ks < 4; ++ks) {
      const size_t off =
          (((size_t)b * 48 + jt * 4 + n) * 4 + ks) * 512 + (size_t)l * 8;
      Bh[n][ks] = *reinterpret_cast<const short8v*>(VFh + off);
      Bl[n][ks] = *reinterpret_cast<const short8v*>(VFl + off);
    }

  f32x4 smax[4];
#pragma unroll
  for (int n = 0; n < 4; ++n)
#pragma unroll
    for (int q = 0; q < 4; ++q) smax[n][q] = -3.4e38f;

  for (int f = 0; f < F_; ++f) {
    const size_t abase = ((size_t)(b * F_ + f) * 48 + it * 4 + w) * 4;
    short8v Ah[4], Al[4];
#pragma unroll
    for (int ks = 0; ks < 4; ++ks) {
      const size_t off = (abase + ks) * 512 + (size_t)l * 8;
      Ah[ks] = *reinterpret_cast<const short8v*>(UFh + off);
      Al[ks] = *reinterpret_cast<const short8v*>(UFl + off);
    }
    f32x4 acc[4];
#pragma unroll
    for (int n = 0; n < 4; ++n)
#pragma unroll
      for (int q = 0; q < 4; ++q) acc[n][q] = 0.f;
    __builtin_amdgcn_s_setprio(1);
#pragma unroll
    for (int ks = 0; ks < 4; ++ks)
#pragma unroll
      for (int n = 0; n < 4; ++n) {
        acc[n] = __builtin_amdgcn_mfma_f32_16x16x32_bf16(Ah[ks], Bh[n][ks], acc[n], 0, 0, 0);
        acc[n] = __builtin_amdgcn_mfma_f32_16x16x32_bf16(Al[ks], Bh[n][ks], acc[n], 0, 0, 0);
        acc[n] = __builtin_amdgcn_mfma_f32_16x16x32_bf16(Ah[ks], Bl[n][ks], acc[n], 0, 0, 0);
      }
    __builtin_amdgcn_s_setprio(0);
#pragma unroll
    for (int n = 0; n < 4; ++n)
#pragma unroll
      for (int q = 0; q < 4; ++q) smax[n][q] = fmaxf(smax[n][q], acc[n][q]);
  }

  const int i0 = it * 64 + w * 16 + (l >> 4) * 4;
  const int j0 = jt * 64 + (l & 15);
#pragma unroll
  for (int n = 0; n < 4; ++n)
#pragma unroll
    for (int q = 0; q < 4; ++q)
      S[((size_t)b * T_ + i0 + q) * T_ + j0 + n * 16] = smax[n][q];
}

// ---------------------------------------------------------------------------
// r18_C: softmax -> P bf16 in LDS -> PV via MFMA.  r15_C (verified) with the
// PV chain split into 2 independent accumulators (even/odd ks) to double
// MFMA ILP (the 48-deep single-acc chain was latency-bound), + setprio.
// 512 threads; XCD-pinned b = blk&7.  grid = 384.
// ---------------------------------------------------------------------------
__global__ __launch_bounds__(512) void r18_C(const unsigned short* __restrict__ VPh,
                                             const unsigned short* __restrict__ VPl,
                                             const float* __restrict__ S,
                                             float* __restrict__ O) {
  __shared__ __align__(16) unsigned short sP[16][776];
  __shared__ float sInv[16];
  const int blk = blockIdx.x;
  const int b    = blk & 7;
  const int it16 = blk >> 3;  // 0..47
  const int t  = threadIdx.x;
  const int r  = t >> 5;   // row 0..15
  const int c  = t & 31;   // lane-in-row (32 lanes)

  const float* Srow = S + (size_t)(b * T_ + it16 * 16) * T_;

  float4 buf[6];
  float m = -3.4e38f;
#pragma unroll
  for (int q = 0; q < 6; ++q) {
    const int j4 = c + q * 32;
    const float4 x = *reinterpret_cast<const float4*>(&Srow[r * T_ + j4 * 4]);
    buf[q] = x;
    m = fmaxf(m, fmaxf(fmaxf(x.x, x.y), fmaxf(x.z, x.w)));
  }
  m = fmaxf(m, __shfl_xor(m, 1));
  m = fmaxf(m, __shfl_xor(m, 2));
  m = fmaxf(m, __shfl_xor(m, 4));
  m = fmaxf(m, __shfl_xor(m, 8));
  m = fmaxf(m, __shfl_xor(m, 16));

  float l = 0.f;
#pragma unroll
  for (int q = 0; q < 6; ++q) {
    const int j4 = c + q * 32;
    float4 e;
    e.x = expf(buf[q].x - m);
    e.y = expf(buf[q].y - m);
    e.z = expf(buf[q].z - m);
    e.w = expf(buf[q].w - m);
    l += (e.x + e.y) + (e.z + e.w);
    ushort4 pb;
    pb.x = f2bf(e.x); pb.y = f2bf(e.y); pb.z = f2bf(e.z); pb.w = f2bf(e.w);
    *reinterpret_cast<ushort4*>(&sP[r][j4 * 4]) = pb;
  }
  l += __shfl_xor(l, 1);
  l += __shfl_xor(l, 2);
  l += __shfl_xor(l, 4);
  l += __shfl_xor(l, 8);
  l += __shfl_xor(l, 16);
  if (c == 0) sInv[r] = 1.0f / l;
  __syncthreads();

  const int w  = t >> 6;   // 0..7
  const int lv = t & 63;
  f32x4 acc0, acc1;
#pragma unroll
  for (int q = 0; q < 4; ++q) { acc0[q] = 0.f; acc1[q] = 0.f; }

  const int arow = lv & 15;
  const int koct = lv >> 4;
  __builtin_amdgcn_s_setprio(1);
#pragma unroll
  for (int ks2 = 0; ks2 < 12; ++ks2) {
    const int ksA = ks2 * 2;
    const int ksB = ks2 * 2 + 1;
    const short8v paA =
        *reinterpret_cast<const short8v*>(&sP[arow][ksA * 32 + koct * 8]);
    const short8v paB =
        *reinterpret_cast<const short8v*>(&sP[arow][ksB * 32 + koct * 8]);
    const size_t fA = (((size_t)b * 8 + w) * 24 + ksA) * 512 + (size_t)lv * 8;
    const size_t fB = (((size_t)b * 8 + w) * 24 + ksB) * 512 + (size_t)lv * 8;
    const short8v vhA = *reinterpret_cast<const short8v*>(VPh + fA);
    const short8v vlA = *reinterpret_cast<const short8v*>(VPl + fA);
    const short8v vhB = *reinterpret_cast<const short8v*>(VPh + fB);
    const short8v vlB = *reinterpret_cast<const short8v*>(VPl + fB);
    acc0 = __builtin_amdgcn_mfma_f32_16x16x32_bf16(paA, vhA, acc0, 0, 0, 0);
    acc1 = __builtin_amdgcn_mfma_f32_16x16x32_bf16(paB, vhB, acc1, 0, 0, 0);
    acc0 = __builtin_amdgcn_mfma_f32_16x16x32_bf16(paA, vlA, acc0, 0, 0, 0);
    acc1 = __builtin_amdgcn_mfma_f32_16x16x32_bf16(paB, vlB, acc1, 0, 0, 0);
  }
  __builtin_amdgcn_s_setprio(0);

  const int hcol = lv & 15;
#pragma unroll
  for (int q = 0; q < 4; ++q) {
    const int irow = (lv >> 4) * 4 + q;
    const float inv = sInv[irow];
    const size_t obase = ((size_t)(b * T_ + it16 * 16 + irow)) * H_;
    O[obase + w * 16 + hcol] = (acc0[q] + acc1[q]) * inv;
  }
}

// ---------------------------------------------------------------------------
extern "C" void kernel_launch(void* const* d_in, const int* in_sizes, int n_in,
                              void* d_out, int out_size, void* d_ws, size_t ws_size,
                              hipStream_t stream) {
  const float* V = (const float*)d_in[0];  // f32 [B,T,H]
  const float* W = (const float*)d_in[1];  // f32 [F,H,H]
  if (n_in >= 2 && in_sizes[0] == F_ * H_ * H_) {
    V = (const float*)d_in[1];
    W = (const float*)d_in[0];
  }
  float* O = (float*)d_out;  // f32 [B,T,H]

  const size_t s_bytes  = (size_t)B_ * T_ * T_ * 4;       // 18,874,368
  const size_t uf_bytes = (size_t)B_ * F_ * H_ * T_ * 2;  // 15,728,640
  const size_t vf_bytes = (size_t)B_ * H_ * T_ * 2;       //  1,572,864
  const size_t wf_bytes = (size_t)F_ * H_ * H_ * 2;       //    327,680
  // Non-overlaid layout (VP gets its own region so all packs can run first).
  const size_t need = s_bytes + 2 * uf_bytes + 4 * vf_bytes + 2 * wf_bytes;  // 57,278,464
  if (ws_size < need) return;

  char* base = (char*)d_ws;
  float* S  = (float*)base;
  unsigned short* UFh = (unsigned short*)(base + s_bytes);
  unsigned short* UFl = (unsigned short*)(base + s_bytes + uf_bytes);
  unsigned short* VFh = (unsigned short*)(base + s_bytes + 2 * uf_bytes);
  unsigned short* VFl = (unsigned short*)(base + s_bytes + 2 * uf_bytes + vf_bytes);
  unsigned short* VPh = (unsigned short*)(base + s_bytes + 2 * uf_bytes + 2 * vf_bytes);
  unsigned short* VPl = (unsigned short*)(base + s_bytes + 2 * uf_bytes + 3 * vf_bytes);
  unsigned short* WFh = (unsigned short*)(base + s_bytes + 2 * uf_bytes + 4 * vf_bytes);
  unsigned short* WFl = (unsigned short*)(base + s_bytes + 2 * uf_bytes + 4 * vf_bytes + wf_bytes);

  r18_P<<<848, 256, 0, stream>>>(V, W, VFh, VFl, WFh, WFl, VPh, VPl);
  r12_A<<<B_ * F_ * (T_ / 64), 256, 0, stream>>>(VFh, VFl, WFh, WFl, UFh, UFl);
  r10_B<<<B_ * (T_ / 64) * (T_ / 64), 256, 0, stream>>>(UFh, UFl, VFh, VFl, S);
  r18_C<<<B_ * (T_ / 16), 512, 0, stream>>>(VPh, VPl, S, O);
}

// Round 19
// 70.515 us; speedup vs baseline: 1.2865x; 1.0174x over previous
//
#include <hip/hip_runtime.h>
#include <hip/hip_bf16.h>

#define B_ 8
#define T_ 768
#define H_ 128
#define F_ 10

using short8v = __attribute__((ext_vector_type(8))) short;
using f32x4   = __attribute__((ext_vector_type(4))) float;

__device__ __forceinline__ float bf2f(unsigned short s) {
  union { unsigned int u; float f; } w;
  w.u = ((unsigned int)s) << 16;
  return w.f;
}
__device__ __forceinline__ unsigned short f2bf(float x) {
  __hip_bfloat16 h = __float2bfloat16(x);  // RN
  return *reinterpret_cast<unsigned short*>(&h);
}
union Pk8 { uint4 u4; unsigned short s[8]; };

// ---------------------------------------------------------------------------
// r18_P: fused packers (one launch).  (verified round 18)
//   blk   0..383 : V -> VF row-major frags (K = H)
//   blk 384..463 : W -> WF B-frags (K = h, N = k)
//   blk 464..847 : V -> VP PV-B-frags (K = j, N = h)
// ---------------------------------------------------------------------------
__global__ __launch_bounds__(256) void r18_P(const float* __restrict__ V,
                                             const float* __restrict__ W,
                                             unsigned short* __restrict__ VFh,
                                             unsigned short* __restrict__ VFl,
                                             unsigned short* __restrict__ WFh,
                                             unsigned short* __restrict__ WFl,
                                             unsigned short* __restrict__ VPh,
                                             unsigned short* __restrict__ VPl) {
  const int blk = blockIdx.x;
  if (blk < 384) {
    const int task = blk * 256 + threadIdx.x;
    const int b  = task / (T_ * 16);
    const int r  = task % (T_ * 16);
    const int j  = r >> 4;
    const int ko = r & 15;
    const float* src = V + ((size_t)b * T_ + j) * H_ + ko * 8;
    const float4 v0 = *reinterpret_cast<const float4*>(src);
    const float4 v1 = *reinterpret_cast<const float4*>(src + 4);
    const float vv[8] = {v0.x, v0.y, v0.z, v0.w, v1.x, v1.y, v1.z, v1.w};
    Pk8 hi, lo;
#pragma unroll
    for (int e = 0; e < 8; ++e) {
      const unsigned short h = f2bf(vv[e]);
      hi.s[e] = h;
      lo.s[e] = f2bf(vv[e] - bf2f(h));
    }
    const size_t frag = ((size_t)b * 48 + (j >> 4)) * 4 + (ko >> 2);
    const size_t off = frag * 512 + ((size_t)((j & 15) + 16 * (ko & 3))) * 8;
    *reinterpret_cast<uint4*>(VFh + off) = hi.u4;
    *reinterpret_cast<uint4*>(VFl + off) = lo.u4;
  } else if (blk < 464) {
    const int tid = (blk - 384) * 256 + threadIdx.x;  // < 20480
    const int frag = tid >> 6;
    const int l    = tid & 63;
    const int f    = frag >> 5;
    const int rest = frag & 31;
    const int n    = rest >> 2;
    const int ks   = rest & 3;
    const int k  = n * 16 + (l & 15);
    const int h0 = ks * 32 + ((l >> 4) * 8);
    Pk8 hi, lo;
#pragma unroll
    for (int e = 0; e < 8; ++e) {
      const float v = W[((size_t)f * H_ + h0 + e) * H_ + k];
      const unsigned short hh = f2bf(v);
      hi.s[e] = hh;
      lo.s[e] = f2bf(v - bf2f(hh));
    }
    const size_t off = (size_t)frag * 512 + (size_t)l * 8;
    *reinterpret_cast<uint4*>(WFh + off) = hi.u4;
    *reinterpret_cast<uint4*>(WFl + off) = lo.u4;
  } else {
    const int tid = (blk - 464) * 256 + threadIdx.x;  // < 98304
    const int h    = tid & 127;
    const int rest = tid >> 7;
    const int jo   = rest % 96;
    const int b    = rest / 96;
    const int j0   = jo * 8;
    Pk8 hi, lo;
#pragma unroll
    for (int e = 0; e < 8; ++e) {
      const float v = V[((size_t)b * T_ + j0 + e) * H_ + h];
      const unsigned short hh = f2bf(v);
      hi.s[e] = hh;
      lo.s[e] = f2bf(v - bf2f(hh));
    }
    const size_t frag = ((size_t)b * 8 + (h >> 4)) * 24 + (j0 >> 5);
    const size_t off = frag * 512 + ((size_t)((h & 15) + 16 * ((j0 >> 3) & 3))) * 8;
    *reinterpret_cast<uint4*>(VPh + off) = hi.u4;
    *reinterpret_cast<uint4*>(VPl + off) = lo.u4;
  }
}

// ---------------------------------------------------------------------------
// r12_A: U = V @ W via split-bf16 MFMA -> UF fragments.  (verified, r13 swizzle)
// ---------------------------------------------------------------------------
__global__ __launch_bounds__(256) void r12_A(const unsigned short* __restrict__ VFh,
                                             const unsigned short* __restrict__ VFl,
                                             const unsigned short* __restrict__ WFh,
                                             const unsigned short* __restrict__ WFl,
                                             unsigned short* __restrict__ UFh,
                                             unsigned short* __restrict__ UFl) {
  __shared__ __align__(16) float fl[8192];
  const int blk = blockIdx.x;
  const int x     = blk & 7;        // XCD under round-robin dispatch
  const int local = blk >> 3;       // 0..119
  const int panel = x * 12 + local / 10;  // 0..95 (b,it)-panel
  const int f     = local % 10;
  const int b  = panel / 12;
  const int it = panel % 12;
  const int t  = threadIdx.x;
  const int w  = t >> 6;
  const int l  = t & 63;

  short8v Ah[4], Al[4];
#pragma unroll
  for (int ks = 0; ks < 4; ++ks) {
    const size_t off = (((size_t)b * 48 + it * 4 + w) * 4 + ks) * 512 + (size_t)l * 8;
    Ah[ks] = *reinterpret_cast<const short8v*>(VFh + off);
    Al[ks] = *reinterpret_cast<const short8v*>(VFl + off);
  }

  f32x4 acc[8];
#pragma unroll
  for (int n = 0; n < 8; ++n)
#pragma unroll
    for (int q = 0; q < 4; ++q) acc[n][q] = 0.f;

#pragma unroll
  for (int n = 0; n < 8; ++n)
#pragma unroll
    for (int ks = 0; ks < 4; ++ks) {
      const size_t off = ((size_t)(f * 8 + n) * 4 + ks) * 512 + (size_t)l * 8;
      const short8v bh = *reinterpret_cast<const short8v*>(WFh + off);
      const short8v bl = *reinterpret_cast<const short8v*>(WFl + off);
      acc[n] = __builtin_amdgcn_mfma_f32_16x16x32_bf16(Ah[ks], bh, acc[n], 0, 0, 0);
      acc[n] = __builtin_amdgcn_mfma_f32_16x16x32_bf16(Al[ks], bh, acc[n], 0, 0, 0);
      acc[n] = __builtin_amdgcn_mfma_f32_16x16x32_bf16(Ah[ks], bl, acc[n], 0, 0, 0);
    }

#pragma unroll
  for (int n = 0; n < 8; ++n)
#pragma unroll
    for (int q = 0; q < 4; ++q) {
      const int i_loc = w * 16 + (l >> 4) * 4 + q;
      const int k = n * 16 + (l & 15);
      const int ll = (i_loc & 15) + 16 * ((k >> 3) & 3);
      fl[((w * 4 + (k >> 5)) << 9) + ll * 8 + (k & 7)] = acc[n][q];
    }
  __syncthreads();
  const size_t ufbase = ((size_t)(b * F_ + f) * 192 + it * 16) * 512;
#pragma unroll
  for (int rr = 0; rr < 4; ++rr) {
    const int idx = rr * 2048 + t * 8;
    const float4 v0 = *reinterpret_cast<const float4*>(&fl[idx]);
    const float4 v1 = *reinterpret_cast<const float4*>(&fl[idx + 4]);
    const float vv[8] = {v0.x, v0.y, v0.z, v0.w, v1.x, v1.y, v1.z, v1.w};
    Pk8 hi, lo;
#pragma unroll
    for (int e = 0; e < 8; ++e) {
      const unsigned short h = f2bf(vv[e]);
      hi.s[e] = h;
      lo.s[e] = f2bf(vv[e] - bf2f(h));
    }
    *reinterpret_cast<uint4*>(UFh + ufbase + idx) = hi.u4;
    *reinterpret_cast<uint4*>(UFl + ufbase + idx) = lo.u4;
  }
}

// ---------------------------------------------------------------------------
// r19_B: S = max_f U_f V^T via split-bf16 MFMA.  Identical tile shape to the
// verified r10_B (4 waves, 16i x 64j per wave, all 10 f), plus:
//   (1) __launch_bounds__(256, 1): allow high VGPR so the B-fragment set
//       (128 VGPR) is genuinely register-resident (r16's VGPR=96 proved the
//       default allocator remats operand loads -> ~40 L2 loads per f-iter);
//   (2) A-fragment double-buffer across the fully-unrolled f-loop (static
//       buffer indices), prefetching f+1 under f's 48 MFMAs;
//   (3) setprio around the MFMA cluster (kept from round 18).
// Same r13 XCD panel swizzle.  grid = 1152.
// ---------------------------------------------------------------------------
__global__ __launch_bounds__(256, 1) void r19_B(const unsigned short* __restrict__ UFh,
                                                const unsigned short* __restrict__ UFl,
                                                const unsigned short* __restrict__ VFh,
                                                const unsigned short* __restrict__ VFl,
                                                float* __restrict__ S) {
  const int blk = blockIdx.x;
  const int x     = blk & 7;
  const int local = blk >> 3;             // 0..143
  const int panel = x * 12 + local / 12;  // 0..95
  const int jt    = local % 12;
  const int b  = panel / 12;
  const int it = panel % 12;
  const int w  = threadIdx.x >> 6;
  const int l  = threadIdx.x & 63;

  // B fragments: register-resident across the whole f-loop
  short8v Bh[4][4], Bl[4][4];
#pragma unroll
  for (int n = 0; n < 4; ++n)
#pragma unroll
    for (int ks = 0; ks < 4; ++ks) {
      const size_t off =
          (((size_t)b * 48 + jt * 4 + n) * 4 + ks) * 512 + (size_t)l * 8;
      Bh[n][ks] = *reinterpret_cast<const short8v*>(VFh + off);
      Bl[n][ks] = *reinterpret_cast<const short8v*>(VFl + off);
    }

  f32x4 smax[4];
#pragma unroll
  for (int n = 0; n < 4; ++n)
#pragma unroll
    for (int q = 0; q < 4; ++q) smax[n][q] = -3.4e38f;

  // A double-buffer; f-loop fully unrolled -> static buffer indices
  short8v Ah[2][4], Al[2][4];
#pragma unroll
  for (int ks = 0; ks < 4; ++ks) {
    const size_t off =
        (((size_t)(b * F_ + 0) * 48 + it * 4 + w) * 4 + ks) * 512 + (size_t)l * 8;
    Ah[0][ks] = *reinterpret_cast<const short8v*>(UFh + off);
    Al[0][ks] = *reinterpret_cast<const short8v*>(UFl + off);
  }

#pragma unroll
  for (int f = 0; f < F_; ++f) {
    const int cur = f & 1;
    const int nxt = cur ^ 1;
    if (f + 1 < F_) {
#pragma unroll
      for (int ks = 0; ks < 4; ++ks) {
        const size_t off =
            (((size_t)(b * F_ + f + 1) * 48 + it * 4 + w) * 4 + ks) * 512 +
            (size_t)l * 8;
        Ah[nxt][ks] = *reinterpret_cast<const short8v*>(UFh + off);
        Al[nxt][ks] = *reinterpret_cast<const short8v*>(UFl + off);
      }
    }
    f32x4 acc[4];
#pragma unroll
    for (int n = 0; n < 4; ++n)
#pragma unroll
      for (int q = 0; q < 4; ++q) acc[n][q] = 0.f;
    __builtin_amdgcn_s_setprio(1);
#pragma unroll
    for (int ks = 0; ks < 4; ++ks)
#pragma unroll
      for (int n = 0; n < 4; ++n) {
        acc[n] = __builtin_amdgcn_mfma_f32_16x16x32_bf16(Ah[cur][ks], Bh[n][ks], acc[n], 0, 0, 0);
        acc[n] = __builtin_amdgcn_mfma_f32_16x16x32_bf16(Al[cur][ks], Bh[n][ks], acc[n], 0, 0, 0);
        acc[n] = __builtin_amdgcn_mfma_f32_16x16x32_bf16(Ah[cur][ks], Bl[n][ks], acc[n], 0, 0, 0);
      }
    __builtin_amdgcn_s_setprio(0);
#pragma unroll
    for (int n = 0; n < 4; ++n)
#pragma unroll
      for (int q = 0; q < 4; ++q) smax[n][q] = fmaxf(smax[n][q], acc[n][q]);
  }

  const int i0 = it * 64 + w * 16 + (l >> 4) * 4;
  const int j0 = jt * 64 + (l & 15);
#pragma unroll
  for (int n = 0; n < 4; ++n)
#pragma unroll
    for (int q = 0; q < 4; ++q)
      S[((size_t)b * T_ + i0 + q) * T_ + j0 + n * 16] = smax[n][q];
}

// ---------------------------------------------------------------------------
// r18_C: softmax -> P bf16 in LDS -> PV via MFMA (2 independent acc chains).
// (verified round 18)  512 threads; XCD-pinned b = blk&7.  grid = 384.
// ---------------------------------------------------------------------------
__global__ __launch_bounds__(512) void r18_C(const unsigned short* __restrict__ VPh,
                                             const unsigned short* __restrict__ VPl,
                                             const float* __restrict__ S,
                                             float* __restrict__ O) {
  __shared__ __align__(16) unsigned short sP[16][776];
  __shared__ float sInv[16];
  const int blk = blockIdx.x;
  const int b    = blk & 7;
  const int it16 = blk >> 3;  // 0..47
  const int t  = threadIdx.x;
  const int r  = t >> 5;   // row 0..15
  const int c  = t & 31;   // lane-in-row (32 lanes)

  const float* Srow = S + (size_t)(b * T_ + it16 * 16) * T_;

  float4 buf[6];
  float m = -3.4e38f;
#pragma unroll
  for (int q = 0; q < 6; ++q) {
    const int j4 = c + q * 32;
    const float4 x = *reinterpret_cast<const float4*>(&Srow[r * T_ + j4 * 4]);
    buf[q] = x;
    m = fmaxf(m, fmaxf(fmaxf(x.x, x.y), fmaxf(x.z, x.w)));
  }
  m = fmaxf(m, __shfl_xor(m, 1));
  m = fmaxf(m, __shfl_xor(m, 2));
  m = fmaxf(m, __shfl_xor(m, 4));
  m = fmaxf(m, __shfl_xor(m, 8));
  m = fmaxf(m, __shfl_xor(m, 16));

  float l = 0.f;
#pragma unroll
  for (int q = 0; q < 6; ++q) {
    const int j4 = c + q * 32;
    float4 e;
    e.x = expf(buf[q].x - m);
    e.y = expf(buf[q].y - m);
    e.z = expf(buf[q].z - m);
    e.w = expf(buf[q].w - m);
    l += (e.x + e.y) + (e.z + e.w);
    ushort4 pb;
    pb.x = f2bf(e.x); pb.y = f2bf(e.y); pb.z = f2bf(e.z); pb.w = f2bf(e.w);
    *reinterpret_cast<ushort4*>(&sP[r][j4 * 4]) = pb;
  }
  l += __shfl_xor(l, 1);
  l += __shfl_xor(l, 2);
  l += __shfl_xor(l, 4);
  l += __shfl_xor(l, 8);
  l += __shfl_xor(l, 16);
  if (c == 0) sInv[r] = 1.0f / l;
  __syncthreads();

  const int w  = t >> 6;   // 0..7
  const int lv = t & 63;
  f32x4 acc0, acc1;
#pragma unroll
  for (int q = 0; q < 4; ++q) { acc0[q] = 0.f; acc1[q] = 0.f; }

  const int arow = lv & 15;
  const int koct = lv >> 4;
  __builtin_amdgcn_s_setprio(1);
#pragma unroll
  for (int ks2 = 0; ks2 < 12; ++ks2) {
    const int ksA = ks2 * 2;
    const int ksB = ks2 * 2 + 1;
    const short8v paA =
        *reinterpret_cast<const short8v*>(&sP[arow][ksA * 32 + koct * 8]);
    const short8v paB =
        *reinterpret_cast<const short8v*>(&sP[arow][ksB * 32 + koct * 8]);
    const size_t fA = (((size_t)b * 8 + w) * 24 + ksA) * 512 + (size_t)lv * 8;
    const size_t fB = (((size_t)b * 8 + w) * 24 + ksB) * 512 + (size_t)lv * 8;
    const short8v vhA = *reinterpret_cast<const short8v*>(VPh + fA);
    const short8v vlA = *reinterpret_cast<const short8v*>(VPl + fA);
    const short8v vhB = *reinterpret_cast<const short8v*>(VPh + fB);
    const short8v vlB = *reinterpret_cast<const short8v*>(VPl + fB);
    acc0 = __builtin_amdgcn_mfma_f32_16x16x32_bf16(paA, vhA, acc0, 0, 0, 0);
    acc1 = __builtin_amdgcn_mfma_f32_16x16x32_bf16(paB, vhB, acc1, 0, 0, 0);
    acc0 = __builtin_amdgcn_mfma_f32_16x16x32_bf16(paA, vlA, acc0, 0, 0, 0);
    acc1 = __builtin_amdgcn_mfma_f32_16x16x32_bf16(paB, vlB, acc1, 0, 0, 0);
  }
  __builtin_amdgcn_s_setprio(0);

  const int hcol = lv & 15;
#pragma unroll
  for (int q = 0; q < 4; ++q) {
    const int irow = (lv >> 4) * 4 + q;
    const float inv = sInv[irow];
    const size_t obase = ((size_t)(b * T_ + it16 * 16 + irow)) * H_;
    O[obase + w * 16 + hcol] = (acc0[q] + acc1[q]) * inv;
  }
}

// ---------------------------------------------------------------------------
extern "C" void kernel_launch(void* const* d_in, const int* in_sizes, int n_in,
                              void* d_out, int out_size, void* d_ws, size_t ws_size,
                              hipStream_t stream) {
  const float* V = (const float*)d_in[0];  // f32 [B,T,H]
  const float* W = (const float*)d_in[1];  // f32 [F,H,H]
  if (n_in >= 2 && in_sizes[0] == F_ * H_ * H_) {
    V = (const float*)d_in[1];
    W = (const float*)d_in[0];
  }
  float* O = (float*)d_out;  // f32 [B,T,H]

  const size_t s_bytes  = (size_t)B_ * T_ * T_ * 4;       // 18,874,368
  const size_t uf_bytes = (size_t)B_ * F_ * H_ * T_ * 2;  // 15,728,640
  const size_t vf_bytes = (size_t)B_ * H_ * T_ * 2;       //  1,572,864
  const size_t wf_bytes = (size_t)F_ * H_ * H_ * 2;       //    327,680
  const size_t need = s_bytes + 2 * uf_bytes + 4 * vf_bytes + 2 * wf_bytes;  // 57,278,464
  if (ws_size < need) return;

  char* base = (char*)d_ws;
  float* S  = (float*)base;
  unsigned short* UFh = (unsigned short*)(base + s_bytes);
  unsigned short* UFl = (unsigned short*)(base + s_bytes + uf_bytes);
  unsigned short* VFh = (unsigned short*)(base + s_bytes + 2 * uf_bytes);
  unsigned short* VFl = (unsigned short*)(base + s_bytes + 2 * uf_bytes + vf_bytes);
  unsigned short* VPh = (unsigned short*)(base + s_bytes + 2 * uf_bytes + 2 * vf_bytes);
  unsigned short* VPl = (unsigned short*)(base + s_bytes + 2 * uf_bytes + 3 * vf_bytes);
  unsigned short* WFh = (unsigned short*)(base + s_bytes + 2 * uf_bytes + 4 * vf_bytes);
  unsigned short* WFl = (unsigned short*)(base + s_bytes + 2 * uf_bytes + 4 * vf_bytes + wf_bytes);

  r18_P<<<848, 256, 0, stream>>>(V, W, VFh, VFl, WFh, WFl, VPh, VPl);
  r12_A<<<B_ * F_ * (T_ / 64), 256, 0, stream>>>(VFh, VFl, WFh, WFl, UFh, UFl);
  r19_B<<<B_ * (T_ / 64) * (T_ / 64), 256, 0, stream>>>(UFh, UFl, VFh, VFl, S);
  r18_C<<<B_ * (T_ / 16), 512, 0, stream>>>(VPh, VPl, S, O);
}